// Round 6
// baseline (225.109 us; speedup 1.0000x reference)
//
#include <hip/hip_runtime.h>
#include <hip/hip_bf16.h>
#include <hip/hip_fp16.h>

// CrossAttention fused pipeline for MI355X (gfx950).
// B=2, S=2048, D=1024, H=16, dh=64. Internal compute fp16 + f32 MFMA accum.

#define D_MODEL 1024
#define NHEAD   16
#define DH      64
#define SEQ     2048
#define BATCH   2
#define MTOT    (BATCH*SEQ)   // 4096

typedef _Float16 f16;
typedef _Float16 f16x8 __attribute__((ext_vector_type(8)));
typedef _Float16 f16x4 __attribute__((ext_vector_type(4)));
typedef float    f32x4 __attribute__((ext_vector_type(4)));

// base-2 exp: v_exp_f32 directly (log2e pre-folded into Q fragments)
#define EXP2F(x) __builtin_amdgcn_exp2f(x)

// ---- async global->LDS (16B per lane). LDS dest must be linear: base + lane*16.
__device__ __forceinline__ void gload_lds16(const void* g, void* l) {
  typedef __attribute__((address_space(1))) const unsigned int* gp_t;
  typedef __attribute__((address_space(3))) unsigned int*       lp_t;
  __builtin_amdgcn_global_load_lds((gp_t)g, (lp_t)l, 16, 0, 0);
}

// ---------------- f32 -> f16 convert (all 5 tensors in one launch) ----------------
__global__ __launch_bounds__(256)
void cvt5_kernel(const float* __restrict__ s0, f16* __restrict__ d0, int n0,
                 const float* __restrict__ s1, f16* __restrict__ d1, int n1,
                 const float* __restrict__ s2, f16* __restrict__ d2, int n2,
                 const float* __restrict__ s3, f16* __restrict__ d3, int n3,
                 const float* __restrict__ s4, f16* __restrict__ d4, int n4_) {
  const float* s; f16* d; int n;
  switch (blockIdx.y) {
    case 0: s = s0; d = d0; n = n0; break;
    case 1: s = s1; d = d1; n = n1; break;
    case 2: s = s2; d = d2; n = n2; break;
    case 3: s = s3; d = d3; n = n3; break;
    default: s = s4; d = d4; n = n4_; break;
  }
  int i = blockIdx.x * blockDim.x + threadIdx.x;
  if (i < n) {
    float4 v = reinterpret_cast<const float4*>(s)[i];
    f16x4 h;
    h[0] = (f16)v.x; h[1] = (f16)v.y; h[2] = (f16)v.z; h[3] = (f16)v.w;
    reinterpret_cast<f16x4*>(d)[i] = h;
  }
}

// ---------------- QKV projection GEMM ----------------
// C[r][c] = sum_k A[r][k] * W[c][k] + bias[c]
// A: [4096][1024] f16, W: [1024][1024] f16 (torch [out,in]).
// mode 0: Q -> [4096][1024]; mode 1: K -> [4096][1024];
// mode 2: V -> transposed Vt[b][h][dd][s]  ([B*H][64][2048]), 8B packed stores
__global__ __launch_bounds__(256)
void qkv_gemm(const f16* __restrict__ dec_h, const f16* __restrict__ enc_h,
              const f16* __restrict__ Wqh, const f16* __restrict__ Wkh, const f16* __restrict__ Wvh,
              const float* __restrict__ bq, const float* __restrict__ bk, const float* __restrict__ bv,
              f16* __restrict__ Qh, f16* __restrict__ Kh, f16* __restrict__ Vth)
{
  __shared__ f16 Ash[128 * 64];   // [row][k]  row stride 128B
  __shared__ f16 Bsh[128 * 64];   // [n][k]

  const int mode = blockIdx.z;
  const f16* A     = (mode == 0) ? dec_h : enc_h;
  const f16* W     = (mode == 0) ? Wqh : (mode == 1) ? Wkh : Wvh;
  const float* bias= (mode == 0) ? bq  : (mode == 1) ? bk  : bv;
  f16* out         = (mode == 0) ? Qh  : (mode == 1) ? Kh  : Vth;

  const int tid  = threadIdx.x;
  const int lane = tid & 63;
  const int wave = tid >> 6;
  const int wr = wave >> 1, wc = wave & 1;   // 2x2 waves, each owns 64x64 of C
  const int bm = blockIdx.x, bn = blockIdx.y;
  const int l15 = lane & 15, lg = lane >> 4;

  f32x4 acc[4][4] = {};

  for (int k0 = 0; k0 < D_MODEL; k0 += 64) {
    __syncthreads();
#pragma unroll
    for (int it = 0; it < 4; ++it) {
      int off = it * 4096 + tid * 16;      // byte offset in 16KB tile
      int row = off >> 7, colb = off & 127;
      gload_lds16((const char*)A + (size_t)(bm*128 + row) * 2048 + k0*2 + colb,
                  (char*)Ash + off);
      gload_lds16((const char*)W + (size_t)(bn*128 + row) * 2048 + k0*2 + colb,
                  (char*)Bsh + off);
    }
    asm volatile("s_waitcnt vmcnt(0)" ::: "memory");
    __syncthreads();
#pragma unroll
    for (int ks = 0; ks < 2; ++ks) {
      f16x8 af[4], bf[4];
#pragma unroll
      for (int m = 0; m < 4; ++m)
        af[m] = *reinterpret_cast<const f16x8*>((const char*)Ash + (wr*64 + m*16 + l15)*128 + ks*64 + lg*16);
#pragma unroll
      for (int n = 0; n < 4; ++n)
        bf[n] = *reinterpret_cast<const f16x8*>((const char*)Bsh + (wc*64 + n*16 + l15)*128 + ks*64 + lg*16);
#pragma unroll
      for (int m = 0; m < 4; ++m)
#pragma unroll
        for (int n = 0; n < 4; ++n)
          acc[m][n] = __builtin_amdgcn_mfma_f32_16x16x32_f16(af[m], bf[n], acc[m][n], 0, 0, 0);
    }
  }

  // epilogue: C/D layout col = lane&15, row = (lane>>4)*4 + j   [m89-verified]
#pragma unroll
  for (int m = 0; m < 4; ++m) {
    int rowg = bm*128 + wr*64 + m*16 + lg*4;
#pragma unroll
    for (int n = 0; n < 4; ++n) {
      int colg = bn*128 + wc*64 + n*16 + l15;
      float bvv = bias[colg];
      if (mode < 2) {
#pragma unroll
        for (int j = 0; j < 4; ++j)
          out[(size_t)(rowg + j) * D_MODEL + colg] = (f16)(acc[m][n][j] + bvv);
      } else {
        // Vt[(b*16+h)*64+dd][s], s = rowg..rowg+3 consecutive -> one 8B store
        int b = rowg >> 11, s = rowg & 2047;
        int hh = colg >> 6, dd = colg & 63;
        f16x4 pv;
#pragma unroll
        for (int j = 0; j < 4; ++j) pv[j] = (f16)(acc[m][n][j] + bvv);
        *reinterpret_cast<f16x4*>(out + (((size_t)((b*NHEAD + hh)*DH + dd)) << 11) + s) = pv;
      }
    }
  }
}

// ---------------- flash attention v5 ----------------
// Swapped QK^T (S^T = mfma(K,Q)), per-lane softmax (q = lane&15), defer-max,
// reg-staged K/V, log2e folded into Q (exp2 path), 32 q-rows PER WAVE
// (two 16-q sub-tiles) to amortize the shared K/V LDS fragment reads.
// Q,K: [4096][1024] f16. Vt: [B*H][64][2048] f16. Z: [B*H][2048][64] f32.
// NOTE: reference applies NO 1/sqrt(dh) scaling.
__global__ __launch_bounds__(256)
void attn_kernel(const f16* __restrict__ Q, const f16* __restrict__ K,
                 const f16* __restrict__ Vt, float* __restrict__ Z)
{
  __shared__ f16 Klds[64 * 64];       // [kv][d]   128B rows, XOR-swizzled
  __shared__ f16 Vlds[64 * 64];       // [dd][kv]  128B rows, XOR-swizzled
  __shared__ f16 Plds[4][2048];       // per wave: [qt][16 q][64 kk], XOR-swizzled

  const int tid = threadIdx.x, lane = tid & 63, wave = tid >> 6;
  const int l15 = lane & 15, lg = lane >> 4;
  const int qb = blockIdx.x;          // 0..15 (q block of 128)
  const int bh = blockIdx.y;          // 0..31
  const int b = bh >> 4, h = bh & 15;

  // Q fragments (B operand of swapped QK), log2e pre-folded:
  // lane holds Q[q0+l15][ks*32 + lg*8 + 0..7] * log2(e)
  f16x8 qf[2][2];
#pragma unroll
  for (int qt = 0; qt < 2; ++qt) {
    const int qrow = qb*128 + wave*32 + qt*16 + l15;
#pragma unroll
    for (int ks = 0; ks < 2; ++ks) {
      f16x8 v = *reinterpret_cast<const f16x8*>(
          Q + ((size_t)(b*SEQ + qrow)*D_MODEL + h*DH + ks*32 + lg*8));
#pragma unroll
      for (int i = 0; i < 8; ++i) v[i] = (f16)((float)v[i] * 1.44269504f);
      qf[qt][ks] = v;
    }
  }

  f32x4 oacc[2][4] = {};
  float mrun[2] = {-__builtin_inff(), -__builtin_inff()};
  float lrun[2] = {0.f, 0.f};

  const char* Kbase = (const char*)(K  + ((size_t)b*SEQ*D_MODEL + h*DH));   // + kv*2048B
  const char* Vbase = (const char*)(Vt + ((size_t)bh*DH*SEQ));              // + dd*4096B + s*2B

  // -------- reg staging (T14): global -> regs (linear), later ds_write (swizzled)
  uint4 kr0, kr1, vr0, vr1;
  const int off0 = tid*16,        r0 = off0 >> 7, c0 = off0 & 127;
  const int off1 = 4096 + tid*16, r1 = off1 >> 7, c1 = off1 & 127;
  const int s0 = off0 ^ ((r0 & 7) << 4);
  const int s1 = off1 ^ ((r1 & 7) << 4);

  auto LOADG = [&](int kb) {
    kr0 = *reinterpret_cast<const uint4*>(Kbase + (size_t)(kb*64 + r0)*2048 + c0);
    vr0 = *reinterpret_cast<const uint4*>(Vbase + (size_t)r0*4096 + kb*128 + c0);
    kr1 = *reinterpret_cast<const uint4*>(Kbase + (size_t)(kb*64 + r1)*2048 + c1);
    vr1 = *reinterpret_cast<const uint4*>(Vbase + (size_t)r1*4096 + kb*128 + c1);
  };
  auto WRITELDS = [&]() {
    *reinterpret_cast<uint4*>((char*)Klds + s0) = kr0;
    *reinterpret_cast<uint4*>((char*)Vlds + s0) = vr0;
    *reinterpret_cast<uint4*>((char*)Klds + s1) = kr1;
    *reinterpret_cast<uint4*>((char*)Vlds + s1) = vr1;
  };

  LOADG(0);
  WRITELDS();
  __syncthreads();

  for (int kb = 0; kb < SEQ/64; ++kb) {
    if (kb + 1 < SEQ/64) LOADG(kb + 1);   // latency hides under compute below

    // S^T = K Q^T : sacc[qt][n] tile has col=q=l15, row kk = n*16 + lg*4 + j
    f32x4 sacc[2][4] = {};
    __builtin_amdgcn_s_setprio(1);
#pragma unroll
    for (int ks = 0; ks < 2; ++ks) {
#pragma unroll
      for (int n = 0; n < 4; ++n) {
        int r = n*16 + l15;
        f16x8 kf = *reinterpret_cast<const f16x8*>(
            (const char*)Klds + r*128 + ((ks*64 + lg*16) ^ ((r & 7) << 4)));
        sacc[0][n] = __builtin_amdgcn_mfma_f32_16x16x32_f16(kf, qf[0][ks], sacc[0][n], 0, 0, 0);
        sacc[1][n] = __builtin_amdgcn_mfma_f32_16x16x32_f16(kf, qf[1][ks], sacc[1][n], 0, 0, 0);
      }
    }
    __builtin_amdgcn_s_setprio(0);

    // per-lane row max (16 kk values per qt), then 2 cross-group rounds
    float mt[2];
#pragma unroll
    for (int qt = 0; qt < 2; ++qt) {
      float m = fmaxf(fmaxf(sacc[qt][0][0], sacc[qt][0][1]),
                      fmaxf(sacc[qt][0][2], sacc[qt][0][3]));
#pragma unroll
      for (int n = 1; n < 4; ++n)
        m = fmaxf(m, fmaxf(fmaxf(sacc[qt][n][0], sacc[qt][n][1]),
                           fmaxf(sacc[qt][n][2], sacc[qt][n][3])));
      m = fmaxf(m, __shfl_xor(m, 16));
      m = fmaxf(m, __shfl_xor(m, 32));
      mt[qt] = m;
    }

    // defer-max (T13, log2 units: 8*log2e ~= 11.54)
    if (!__all(mt[0] <= mrun[0] + 11.5f && mt[1] <= mrun[1] + 11.5f)) {
#pragma unroll
      for (int qt = 0; qt < 2; ++qt) {
        float mn = fmaxf(mrun[qt], mt[qt]);
        float sc = EXP2F(mrun[qt] - mn);
        mrun[qt] = mn;
        lrun[qt] *= sc;
#pragma unroll
        for (int j = 0; j < 4; ++j) {
          float scJ = __shfl(sc, (lane & 48) | (((lane >> 4) << 2) + j), 64);
#pragma unroll
          for (int n = 0; n < 4; ++n) oacc[qt][n][j] *= scJ;
        }
      }
    }

    // P = exp2(S - mrun) (bounded by 2^11.5), packed 4-wide writes along kk
#pragma unroll
    for (int qt = 0; qt < 2; ++qt) {
      float rs = 0.f;
#pragma unroll
      for (int n = 0; n < 4; ++n) {
        f16x4 pp;
#pragma unroll
        for (int j = 0; j < 4; ++j) {
          float p = EXP2F(sacc[qt][n][j] - mrun[qt]);
          rs += p;
          pp[j] = (f16)p;
        }
        *reinterpret_cast<f16x4*>((char*)&Plds[wave][0] + qt*2048 + l15*128 +
                                  ((n*32 + lg*8) ^ ((l15 & 7) << 4))) = pp;
      }
      rs += __shfl_xor(rs, 16);
      rs += __shfl_xor(rs, 32);
      lrun[qt] += rs;
    }

    // O += P @ V  (A = P rows q=l15; B = V^T rows d)
    __builtin_amdgcn_s_setprio(1);
#pragma unroll
    for (int ks = 0; ks < 2; ++ks) {
      f16x8 pf0 = *reinterpret_cast<const f16x8*>(
          (const char*)&Plds[wave][0] + l15*128 + ((ks*64 + lg*16) ^ ((l15 & 7) << 4)));
      f16x8 pf1 = *reinterpret_cast<const f16x8*>(
          (const char*)&Plds[wave][0] + 2048 + l15*128 + ((ks*64 + lg*16) ^ ((l15 & 7) << 4)));
#pragma unroll
      for (int n = 0; n < 4; ++n) {
        int r = n*16 + l15;
        f16x8 vf = *reinterpret_cast<const f16x8*>(
            (const char*)Vlds + r*128 + ((ks*64 + lg*16) ^ ((r & 7) << 4)));
        oacc[0][n] = __builtin_amdgcn_mfma_f32_16x16x32_f16(pf0, vf, oacc[0][n], 0, 0, 0);
        oacc[1][n] = __builtin_amdgcn_mfma_f32_16x16x32_f16(pf1, vf, oacc[1][n], 0, 0, 0);
      }
    }
    __builtin_amdgcn_s_setprio(0);

    __syncthreads();                     // all waves done reading K/V tile kb
    if (kb + 1 < SEQ/64) WRITELDS();     // regs(kb+1) -> LDS (compiler waits vmcnt)
    __syncthreads();                     // tile kb+1 visible
  }

  // epilogue: divide by denom of row q = lg*4+j (owner lane l15' = q, same group)
#pragma unroll
  for (int qt = 0; qt < 2; ++qt) {
    float lJ[4];
#pragma unroll
    for (int j = 0; j < 4; ++j)
      lJ[j] = __shfl(lrun[qt], (lane & 48) | (((lane >> 4) << 2) + j), 64);
#pragma unroll
    for (int n = 0; n < 4; ++n)
#pragma unroll
      for (int j = 0; j < 4; ++j) {
        float v = oacc[qt][n][j] / lJ[j];
        Z[((size_t)bh*SEQ + qb*128 + wave*32 + qt*16 + lg*4 + j)*DH + n*16 + l15] = v;
      }
  }
}

// ---------------- residual + LayerNorm with the raw-memory reshape gather ----------------
// x[b,sq,d] = Z[b*16 + (sq>>7)][((sq&127)<<4) | (d>>6)][d&63] + decoded[b,sq,d]
__global__ __launch_bounds__(256)
void ln_kernel(const float* __restrict__ Z, const float* __restrict__ dec,
               const float* __restrict__ gamma, const float* __restrict__ beta,
               float* __restrict__ out)
{
  const int row = blockIdx.x;            // 0..4095 (b*2048 + sq)
  const int b = row >> 11, sq = row & 2047;
  const int h = sq >> 7;
  const int qbase = (sq & 127) << 4;
  const int t = threadIdx.x;
  const int d = t * 4;
  const int qi = qbase + (d >> 6);

  float4 z4 = *reinterpret_cast<const float4*>(Z + ((size_t)(b*NHEAD + h)*SEQ + qi)*DH + (d & 63));
  float4 dv = *reinterpret_cast<const float4*>(dec + (size_t)row*D_MODEL + d);
  float x0 = z4.x + dv.x, x1 = z4.y + dv.y, x2 = z4.z + dv.z, x3 = z4.w + dv.w;

  float s  = x0 + x1 + x2 + x3;
  float ss = x0*x0 + x1*x1 + x2*x2 + x3*x3;
#pragma unroll
  for (int off = 1; off < 64; off <<= 1) { s += __shfl_xor(s, off); ss += __shfl_xor(ss, off); }

  __shared__ float red[8];
  int wave = t >> 6, lane = t & 63;
  if (lane == 0) { red[wave] = s; red[wave + 4] = ss; }
  __syncthreads();
  s  = red[0] + red[1] + red[2] + red[3];
  ss = red[4] + red[5] + red[6] + red[7];

  float mean = s * (1.f/1024.f);
  float var  = ss * (1.f/1024.f) - mean*mean;
  float rstd = rsqrtf(var + 1e-5f);

  float4 g4 = *reinterpret_cast<const float4*>(gamma + d);
  float4 b4 = *reinterpret_cast<const float4*>(beta + d);
  float4 o;
  o.x = (x0 - mean)*rstd*g4.x + b4.x;
  o.y = (x1 - mean)*rstd*g4.y + b4.y;
  o.z = (x2 - mean)*rstd*g4.z + b4.z;
  o.w = (x3 - mean)*rstd*g4.w + b4.w;
  *reinterpret_cast<float4*>(out + (size_t)row*D_MODEL + d) = o;
}

// ---------------- launch ----------------
extern "C" void kernel_launch(void* const* d_in, const int* in_sizes, int n_in,
                              void* d_out, int out_size, void* d_ws, size_t ws_size,
                              hipStream_t stream) {
  const float* enc   = (const float*)d_in[0];
  const float* dec   = (const float*)d_in[1];
  const float* Wq    = (const float*)d_in[2];
  const float* bq    = (const float*)d_in[3];
  const float* Wk    = (const float*)d_in[4];
  const float* bk    = (const float*)d_in[5];
  const float* Wv    = (const float*)d_in[6];
  const float* bv    = (const float*)d_in[7];
  const float* gamma = (const float*)d_in[8];
  const float* beta  = (const float*)d_in[9];
  float* out = (float*)d_out;
  uint8_t* ws = (uint8_t*)d_ws;

  // workspace layout (62 MB total)
  f16*  enc_h = (f16*)(ws);                       // 8 MB
  f16*  dec_h = (f16*)(ws + (8u  << 20));         // 8 MB
  f16*  Wq_h  = (f16*)(ws + (16u << 20));         // 2 MB
  f16*  Wk_h  = (f16*)(ws + (18u << 20));         // 2 MB
  f16*  Wv_h  = (f16*)(ws + (20u << 20));         // 2 MB
  f16*  Qh    = (f16*)(ws + (22u << 20));         // 8 MB
  f16*  Kh    = (f16*)(ws + (30u << 20));         // 8 MB
  f16*  Vth   = (f16*)(ws + (38u << 20));         // 8 MB  [B*H][64][2048]
  float* Z    = (float*)(ws + (46u << 20));       // 16 MB [B*H][2048][64]

  const int nbig = MTOT * D_MODEL / 4;            // 1M float4 chunks
  const int nw   = D_MODEL * D_MODEL / 4;         // 256K
  cvt5_kernel<<<dim3(nbig/256, 5), 256, 0, stream>>>(
      enc, enc_h, nbig, dec, dec_h, nbig,
      Wq, Wq_h, nw, Wk, Wk_h, nw, Wv, Wv_h, nw);

  qkv_gemm<<<dim3(MTOT/128, D_MODEL/128, 3), 256, 0, stream>>>(
      dec_h, enc_h, Wq_h, Wk_h, Wv_h, bq, bk, bv, Qh, Kh, Vth);

  attn_kernel<<<dim3(SEQ/128, BATCH*NHEAD), 256, 0, stream>>>(Qh, Kh, Vth, Z);

  ln_kernel<<<MTOT, 256, 0, stream>>>(Z, dec, gamma, beta, out);
}

// Round 7
// 221.048 us; speedup vs baseline: 1.0184x; 1.0184x over previous
//
#include <hip/hip_runtime.h>
#include <hip/hip_bf16.h>
#include <hip/hip_fp16.h>

// CrossAttention fused pipeline for MI355X (gfx950).
// B=2, S=2048, D=1024, H=16, dh=64. Internal compute fp16 + f32 MFMA accum.

#define D_MODEL 1024
#define NHEAD   16
#define DH      64
#define SEQ     2048
#define BATCH   2
#define MTOT    (BATCH*SEQ)   // 4096

typedef _Float16 f16;
typedef _Float16 f16x8 __attribute__((ext_vector_type(8)));
typedef _Float16 f16x4 __attribute__((ext_vector_type(4)));
typedef float    f32x4 __attribute__((ext_vector_type(4)));

// base-2 exp: v_exp_f32 directly (log2e pre-folded into Q fragments)
#define EXP2F(x) __builtin_amdgcn_exp2f(x)

// ---------------- QKV projection GEMM (f32 in, f16 out, fused convert) -------
// C[r][c] = sum_k A[r][k] * W[c][k] + bias[c]
// A: [4096][1024] f32, W: [1024][1024] f32 (torch [out,in]).
// mode 0: Q -> [4096][1024] f16; mode 1: K -> [4096][1024] f16;
// mode 2: V -> transposed Vt[b][h][dd][s]  ([B*H][64][2048]) f16.
// Staging: reg-staged (global f32 -> regs early; cvt+swizzled ds_write after
// barrier) — the attn-R4-proven race-free schedule. LDS XOR-swizzled
// (byte ^= (row&7)<<4) on write AND read.
__global__ __launch_bounds__(256)
void qkv_gemm(const float* __restrict__ dec32, const float* __restrict__ enc32,
              const float* __restrict__ Wq32, const float* __restrict__ Wk32,
              const float* __restrict__ Wv32,
              const float* __restrict__ bq, const float* __restrict__ bk, const float* __restrict__ bv,
              f16* __restrict__ Qh, f16* __restrict__ Kh, f16* __restrict__ Vth)
{
  __shared__ f16 Ash[128 * 64];   // [row][k] 128B rows, swizzled
  __shared__ f16 Bsh[128 * 64];   // [n][k]   128B rows, swizzled

  const int mode = blockIdx.z;
  const float* A   = (mode == 0) ? dec32 : enc32;
  const float* W   = (mode == 0) ? Wq32 : (mode == 1) ? Wk32 : Wv32;
  const float* bias= (mode == 0) ? bq   : (mode == 1) ? bk   : bv;
  f16* out         = (mode == 0) ? Qh   : (mode == 1) ? Kh   : Vth;

  const int tid  = threadIdx.x;
  const int lane = tid & 63;
  const int wave = tid >> 6;
  const int wr = wave >> 1, wc = wave & 1;   // 2x2 waves, each owns 64x64 of C
  const int bm = blockIdx.x, bn = blockIdx.y;
  const int l15 = lane & 15, lg = lane >> 4;

  // staging coordinates: 4 chunks of 8 f16 elems per tile per thread
  int srow[4], skc[4], sbyte[4];
#pragma unroll
  for (int c = 0; c < 4; ++c) {
    int flat = c * 2048 + tid * 8;           // f16 element index in 128x64 tile
    srow[c]  = flat >> 6;
    skc[c]   = flat & 63;
    sbyte[c] = (flat * 2) ^ ((srow[c] & 7) << 4);
  }

  f32x4 areg[4][2], wreg[4][2];
  auto LOADG = [&](int k0) {
#pragma unroll
    for (int c = 0; c < 4; ++c) {
      const float* pa = A + (size_t)(bm*128 + srow[c]) * 1024 + k0 + skc[c];
      areg[c][0] = *reinterpret_cast<const f32x4*>(pa);
      areg[c][1] = *reinterpret_cast<const f32x4*>(pa + 4);
      const float* pw = W + (size_t)(bn*128 + srow[c]) * 1024 + k0 + skc[c];
      wreg[c][0] = *reinterpret_cast<const f32x4*>(pw);
      wreg[c][1] = *reinterpret_cast<const f32x4*>(pw + 4);
    }
  };
  auto WRITELDS = [&]() {
#pragma unroll
    for (int c = 0; c < 4; ++c) {
      f16x8 ha, hw;
#pragma unroll
      for (int i = 0; i < 4; ++i) {
        ha[i]     = (f16)areg[c][0][i];
        ha[4 + i] = (f16)areg[c][1][i];
        hw[i]     = (f16)wreg[c][0][i];
        hw[4 + i] = (f16)wreg[c][1][i];
      }
      *reinterpret_cast<f16x8*>((char*)Ash + sbyte[c]) = ha;
      *reinterpret_cast<f16x8*>((char*)Bsh + sbyte[c]) = hw;
    }
  };

  f32x4 acc[4][4] = {};

  LOADG(0);
  WRITELDS();
  __syncthreads();

  for (int k0 = 0; k0 < D_MODEL; k0 += 64) {
    if (k0 + 64 < D_MODEL) LOADG(k0 + 64);   // HBM latency hides under compute

    __builtin_amdgcn_s_setprio(1);
#pragma unroll
    for (int ks = 0; ks < 2; ++ks) {
      f16x8 af[4], bf[4];
#pragma unroll
      for (int m = 0; m < 4; ++m) {
        int r = wr*64 + m*16 + l15;
        af[m] = *reinterpret_cast<const f16x8*>(
            (const char*)Ash + r*128 + ((ks*64 + lg*16) ^ ((r & 7) << 4)));
      }
#pragma unroll
      for (int n = 0; n < 4; ++n) {
        int r = wc*64 + n*16 + l15;
        bf[n] = *reinterpret_cast<const f16x8*>(
            (const char*)Bsh + r*128 + ((ks*64 + lg*16) ^ ((r & 7) << 4)));
      }
#pragma unroll
      for (int m = 0; m < 4; ++m)
#pragma unroll
        for (int n = 0; n < 4; ++n)
          acc[m][n] = __builtin_amdgcn_mfma_f32_16x16x32_f16(af[m], bf[n], acc[m][n], 0, 0, 0);
    }
    __builtin_amdgcn_s_setprio(0);

    __syncthreads();                         // all waves done reading this tile
    if (k0 + 64 < D_MODEL) WRITELDS();       // regs(k0+64) -> LDS
    __syncthreads();                         // next tile visible
  }

  // epilogue: C/D layout col = lane&15, row = (lane>>4)*4 + j   [m89-verified]
#pragma unroll
  for (int m = 0; m < 4; ++m) {
    int rowg = bm*128 + wr*64 + m*16 + lg*4;
#pragma unroll
    for (int n = 0; n < 4; ++n) {
      int colg = bn*128 + wc*64 + n*16 + l15;
      float bvv = bias[colg];
      if (mode < 2) {
#pragma unroll
        for (int j = 0; j < 4; ++j)
          out[(size_t)(rowg + j) * D_MODEL + colg] = (f16)(acc[m][n][j] + bvv);
      } else {
        // Vt[(b*16+h)*64+dd][s], s = rowg..rowg+3 consecutive -> one 8B store
        int b = rowg >> 11, s = rowg & 2047;
        int hh = colg >> 6, dd = colg & 63;
        f16x4 pv;
#pragma unroll
        for (int j = 0; j < 4; ++j) pv[j] = (f16)(acc[m][n][j] + bvv);
        *reinterpret_cast<f16x4*>(out + (((size_t)((b*NHEAD + hh)*DH + dd)) << 11) + s) = pv;
      }
    }
  }
}

// ---------------- flash attention v5 (unchanged from R6, passed) ----------------
// Swapped QK^T (S^T = mfma(K,Q)), per-lane softmax (q = lane&15), defer-max,
// reg-staged K/V, log2e folded into Q (exp2 path), 32 q-rows per wave.
// Q,K: [4096][1024] f16. Vt: [B*H][64][2048] f16. Z: [B*H][2048][64] f32.
// NOTE: reference applies NO 1/sqrt(dh) scaling.
__global__ __launch_bounds__(256)
void attn_kernel(const f16* __restrict__ Q, const f16* __restrict__ K,
                 const f16* __restrict__ Vt, float* __restrict__ Z)
{
  __shared__ f16 Klds[64 * 64];       // [kv][d]   128B rows, XOR-swizzled
  __shared__ f16 Vlds[64 * 64];       // [dd][kv]  128B rows, XOR-swizzled
  __shared__ f16 Plds[4][2048];       // per wave: [qt][16 q][64 kk], XOR-swizzled

  const int tid = threadIdx.x, lane = tid & 63, wave = tid >> 6;
  const int l15 = lane & 15, lg = lane >> 4;
  const int qb = blockIdx.x;          // 0..15 (q block of 128)
  const int bh = blockIdx.y;          // 0..31
  const int b = bh >> 4, h = bh & 15;

  // Q fragments (B operand of swapped QK), log2e pre-folded
  f16x8 qf[2][2];
#pragma unroll
  for (int qt = 0; qt < 2; ++qt) {
    const int qrow = qb*128 + wave*32 + qt*16 + l15;
#pragma unroll
    for (int ks = 0; ks < 2; ++ks) {
      f16x8 v = *reinterpret_cast<const f16x8*>(
          Q + ((size_t)(b*SEQ + qrow)*D_MODEL + h*DH + ks*32 + lg*8));
#pragma unroll
      for (int i = 0; i < 8; ++i) v[i] = (f16)((float)v[i] * 1.44269504f);
      qf[qt][ks] = v;
    }
  }

  f32x4 oacc[2][4] = {};
  float mrun[2] = {-__builtin_inff(), -__builtin_inff()};
  float lrun[2] = {0.f, 0.f};

  const char* Kbase = (const char*)(K  + ((size_t)b*SEQ*D_MODEL + h*DH));   // + kv*2048B
  const char* Vbase = (const char*)(Vt + ((size_t)bh*DH*SEQ));              // + dd*4096B + s*2B

  uint4 kr0, kr1, vr0, vr1;
  const int off0 = tid*16,        r0 = off0 >> 7, c0 = off0 & 127;
  const int off1 = 4096 + tid*16, r1 = off1 >> 7, c1 = off1 & 127;
  const int s0 = off0 ^ ((r0 & 7) << 4);
  const int s1 = off1 ^ ((r1 & 7) << 4);

  auto LOADG = [&](int kb) {
    kr0 = *reinterpret_cast<const uint4*>(Kbase + (size_t)(kb*64 + r0)*2048 + c0);
    vr0 = *reinterpret_cast<const uint4*>(Vbase + (size_t)r0*4096 + kb*128 + c0);
    kr1 = *reinterpret_cast<const uint4*>(Kbase + (size_t)(kb*64 + r1)*2048 + c1);
    vr1 = *reinterpret_cast<const uint4*>(Vbase + (size_t)r1*4096 + kb*128 + c1);
  };
  auto WRITELDS = [&]() {
    *reinterpret_cast<uint4*>((char*)Klds + s0) = kr0;
    *reinterpret_cast<uint4*>((char*)Vlds + s0) = vr0;
    *reinterpret_cast<uint4*>((char*)Klds + s1) = kr1;
    *reinterpret_cast<uint4*>((char*)Vlds + s1) = vr1;
  };

  LOADG(0);
  WRITELDS();
  __syncthreads();

  for (int kb = 0; kb < SEQ/64; ++kb) {
    if (kb + 1 < SEQ/64) LOADG(kb + 1);   // latency hides under compute below

    // S^T = K Q^T : sacc[qt][n] tile has col=q=l15, row kk = n*16 + lg*4 + j
    f32x4 sacc[2][4] = {};
    __builtin_amdgcn_s_setprio(1);
#pragma unroll
    for (int ks = 0; ks < 2; ++ks) {
#pragma unroll
      for (int n = 0; n < 4; ++n) {
        int r = n*16 + l15;
        f16x8 kf = *reinterpret_cast<const f16x8*>(
            (const char*)Klds + r*128 + ((ks*64 + lg*16) ^ ((r & 7) << 4)));
        sacc[0][n] = __builtin_amdgcn_mfma_f32_16x16x32_f16(kf, qf[0][ks], sacc[0][n], 0, 0, 0);
        sacc[1][n] = __builtin_amdgcn_mfma_f32_16x16x32_f16(kf, qf[1][ks], sacc[1][n], 0, 0, 0);
      }
    }
    __builtin_amdgcn_s_setprio(0);

    // per-lane row max (16 kk values per qt), then 2 cross-group rounds
    float mt[2];
#pragma unroll
    for (int qt = 0; qt < 2; ++qt) {
      float m = fmaxf(fmaxf(sacc[qt][0][0], sacc[qt][0][1]),
                      fmaxf(sacc[qt][0][2], sacc[qt][0][3]));
#pragma unroll
      for (int n = 1; n < 4; ++n)
        m = fmaxf(m, fmaxf(fmaxf(sacc[qt][n][0], sacc[qt][n][1]),
                           fmaxf(sacc[qt][n][2], sacc[qt][n][3])));
      m = fmaxf(m, __shfl_xor(m, 16));
      m = fmaxf(m, __shfl_xor(m, 32));
      mt[qt] = m;
    }

    // defer-max (T13, log2 units: 8*log2e ~= 11.54)
    if (!__all(mt[0] <= mrun[0] + 11.5f && mt[1] <= mrun[1] + 11.5f)) {
#pragma unroll
      for (int qt = 0; qt < 2; ++qt) {
        float mn = fmaxf(mrun[qt], mt[qt]);
        float sc = EXP2F(mrun[qt] - mn);
        mrun[qt] = mn;
        lrun[qt] *= sc;
#pragma unroll
        for (int j = 0; j < 4; ++j) {
          float scJ = __shfl(sc, (lane & 48) | (((lane >> 4) << 2) + j), 64);
#pragma unroll
          for (int n = 0; n < 4; ++n) oacc[qt][n][j] *= scJ;
        }
      }
    }

    // P = exp2(S - mrun) (bounded by 2^11.5), packed 4-wide writes along kk
#pragma unroll
    for (int qt = 0; qt < 2; ++qt) {
      float rs = 0.f;
#pragma unroll
      for (int n = 0; n < 4; ++n) {
        f16x4 pp;
#pragma unroll
        for (int j = 0; j < 4; ++j) {
          float p = EXP2F(sacc[qt][n][j] - mrun[qt]);
          rs += p;
          pp[j] = (f16)p;
        }
        *reinterpret_cast<f16x4*>((char*)&Plds[wave][0] + qt*2048 + l15*128 +
                                  ((n*32 + lg*8) ^ ((l15 & 7) << 4))) = pp;
      }
      rs += __shfl_xor(rs, 16);
      rs += __shfl_xor(rs, 32);
      lrun[qt] += rs;
    }

    // O += P @ V  (A = P rows q=l15; B = V^T rows d)
    __builtin_amdgcn_s_setprio(1);
#pragma unroll
    for (int ks = 0; ks < 2; ++ks) {
      f16x8 pf0 = *reinterpret_cast<const f16x8*>(
          (const char*)&Plds[wave][0] + l15*128 + ((ks*64 + lg*16) ^ ((l15 & 7) << 4)));
      f16x8 pf1 = *reinterpret_cast<const f16x8*>(
          (const char*)&Plds[wave][0] + 2048 + l15*128 + ((ks*64 + lg*16) ^ ((l15 & 7) << 4)));
#pragma unroll
      for (int n = 0; n < 4; ++n) {
        int r = n*16 + l15;
        f16x8 vf = *reinterpret_cast<const f16x8*>(
            (const char*)Vlds + r*128 + ((ks*64 + lg*16) ^ ((r & 7) << 4)));
        oacc[0][n] = __builtin_amdgcn_mfma_f32_16x16x32_f16(pf0, vf, oacc[0][n], 0, 0, 0);
        oacc[1][n] = __builtin_amdgcn_mfma_f32_16x16x32_f16(pf1, vf, oacc[1][n], 0, 0, 0);
      }
    }
    __builtin_amdgcn_s_setprio(0);

    __syncthreads();                     // all waves done reading K/V tile kb
    if (kb + 1 < SEQ/64) WRITELDS();     // regs(kb+1) -> LDS (compiler waits vmcnt)
    __syncthreads();                     // tile kb+1 visible
  }

  // epilogue: divide by denom of row q = lg*4+j (owner lane l15' = q, same group)
#pragma unroll
  for (int qt = 0; qt < 2; ++qt) {
    float lJ[4];
#pragma unroll
    for (int j = 0; j < 4; ++j)
      lJ[j] = __shfl(lrun[qt], (lane & 48) | (((lane >> 4) << 2) + j), 64);
#pragma unroll
    for (int n = 0; n < 4; ++n)
#pragma unroll
      for (int j = 0; j < 4; ++j) {
        float v = oacc[qt][n][j] / lJ[j];
        Z[((size_t)bh*SEQ + qb*128 + wave*32 + qt*16 + lg*4 + j)*DH + n*16 + l15] = v;
      }
  }
}

// ---------------- residual + LayerNorm with the raw-memory reshape gather ----------------
// x[b,sq,d] = Z[b*16 + (sq>>7)][((sq&127)<<4) | (d>>6)][d&63] + decoded[b,sq,d]
__global__ __launch_bounds__(256)
void ln_kernel(const float* __restrict__ Z, const float* __restrict__ dec,
               const float* __restrict__ gamma, const float* __restrict__ beta,
               float* __restrict__ out)
{
  const int row = blockIdx.x;            // 0..4095 (b*2048 + sq)
  const int b = row >> 11, sq = row & 2047;
  const int h = sq >> 7;
  const int qbase = (sq & 127) << 4;
  const int t = threadIdx.x;
  const int d = t * 4;
  const int qi = qbase + (d >> 6);

  float4 z4 = *reinterpret_cast<const float4*>(Z + ((size_t)(b*NHEAD + h)*SEQ + qi)*DH + (d & 63));
  float4 dv = *reinterpret_cast<const float4*>(dec + (size_t)row*D_MODEL + d);
  float x0 = z4.x + dv.x, x1 = z4.y + dv.y, x2 = z4.z + dv.z, x3 = z4.w + dv.w;

  float s  = x0 + x1 + x2 + x3;
  float ss = x0*x0 + x1*x1 + x2*x2 + x3*x3;
#pragma unroll
  for (int off = 1; off < 64; off <<= 1) { s += __shfl_xor(s, off); ss += __shfl_xor(ss, off); }

  __shared__ float red[8];
  int wave = t >> 6, lane = t & 63;
  if (lane == 0) { red[wave] = s; red[wave + 4] = ss; }
  __syncthreads();
  s  = red[0] + red[1] + red[2] + red[3];
  ss = red[4] + red[5] + red[6] + red[7];

  float mean = s * (1.f/1024.f);
  float var  = ss * (1.f/1024.f) - mean*mean;
  float rstd = rsqrtf(var + 1e-5f);

  float4 g4 = *reinterpret_cast<const float4*>(gamma + d);
  float4 b4 = *reinterpret_cast<const float4*>(beta + d);
  float4 o;
  o.x = (x0 - mean)*rstd*g4.x + b4.x;
  o.y = (x1 - mean)*rstd*g4.y + b4.y;
  o.z = (x2 - mean)*rstd*g4.z + b4.z;
  o.w = (x3 - mean)*rstd*g4.w + b4.w;
  *reinterpret_cast<float4*>(out + (size_t)row*D_MODEL + d) = o;
}

// ---------------- launch ----------------
extern "C" void kernel_launch(void* const* d_in, const int* in_sizes, int n_in,
                              void* d_out, int out_size, void* d_ws, size_t ws_size,
                              hipStream_t stream) {
  const float* enc   = (const float*)d_in[0];
  const float* dec   = (const float*)d_in[1];
  const float* Wq    = (const float*)d_in[2];
  const float* bq    = (const float*)d_in[3];
  const float* Wk    = (const float*)d_in[4];
  const float* bk    = (const float*)d_in[5];
  const float* Wv    = (const float*)d_in[6];
  const float* bv    = (const float*)d_in[7];
  const float* gamma = (const float*)d_in[8];
  const float* beta  = (const float*)d_in[9];
  float* out = (float*)d_out;
  uint8_t* ws = (uint8_t*)d_ws;

  // workspace layout (40 MB total)
  f16*  Qh    = (f16*)(ws);                       // 8 MB
  f16*  Kh    = (f16*)(ws + (8u  << 20));         // 8 MB
  f16*  Vth   = (f16*)(ws + (16u << 20));         // 8 MB  [B*H][64][2048]
  float* Z    = (float*)(ws + (24u << 20));       // 16 MB [B*H][2048][64]

  qkv_gemm<<<dim3(MTOT/128, D_MODEL/128, 3), 256, 0, stream>>>(
      dec, enc, Wq, Wk, Wv, bq, bk, bv, Qh, Kh, Vth);

  attn_kernel<<<dim3(SEQ/128, BATCH*NHEAD), 256, 0, stream>>>(Qh, Kh, Vth, Z);

  ln_kernel<<<MTOT, 256, 0, stream>>>(Z, dec, gamma, beta, out);
}

// Round 8
// 209.116 us; speedup vs baseline: 1.0765x; 1.0571x over previous
//
#include <hip/hip_runtime.h>
#include <hip/hip_bf16.h>
#include <hip/hip_fp16.h>

// CrossAttention fused pipeline for MI355X (gfx950).
// B=2, S=2048, D=1024, H=16, dh=64. Internal compute fp16 + f32 MFMA accum.
// Pipeline: qkv_gemm (f32->f16 fused convert) -> attn+residual+LN (fused).

#define D_MODEL 1024
#define NHEAD   16
#define DH      64
#define SEQ     2048
#define BATCH   2
#define MTOT    (BATCH*SEQ)   // 4096

typedef _Float16 f16;
typedef _Float16 f16x8 __attribute__((ext_vector_type(8)));
typedef _Float16 f16x4 __attribute__((ext_vector_type(4)));
typedef float    f32x4 __attribute__((ext_vector_type(4)));

// base-2 exp: v_exp_f32 directly (log2e pre-folded into Q fragments)
#define EXP2F(x) __builtin_amdgcn_exp2f(x)

// ---------------- QKV projection GEMM (f32 in, f16 out, fused convert) -------
// C[r][c] = sum_k A[r][k] * W[c][k] + bias[c]
// A: [4096][1024] f32, W: [1024][1024] f32 (torch [out,in]).
// mode 0: Q -> [4096][1024] f16; mode 1: K -> [4096][1024] f16;
// mode 2: V -> transposed Vt[b][h][dd][s]  ([B*H][64][2048]) f16.
// Reg-staged (attn-R4-proven race-free schedule); LDS XOR-swizzled both sides.
__global__ __launch_bounds__(256)
void qkv_gemm(const float* __restrict__ dec32, const float* __restrict__ enc32,
              const float* __restrict__ Wq32, const float* __restrict__ Wk32,
              const float* __restrict__ Wv32,
              const float* __restrict__ bq, const float* __restrict__ bk, const float* __restrict__ bv,
              f16* __restrict__ Qh, f16* __restrict__ Kh, f16* __restrict__ Vth)
{
  __shared__ f16 Ash[128 * 64];   // [row][k] 128B rows, swizzled
  __shared__ f16 Bsh[128 * 64];   // [n][k]   128B rows, swizzled

  const int mode = blockIdx.z;
  const float* A   = (mode == 0) ? dec32 : enc32;
  const float* W   = (mode == 0) ? Wq32 : (mode == 1) ? Wk32 : Wv32;
  const float* bias= (mode == 0) ? bq   : (mode == 1) ? bk   : bv;
  f16* out         = (mode == 0) ? Qh   : (mode == 1) ? Kh   : Vth;

  const int tid  = threadIdx.x;
  const int lane = tid & 63;
  const int wave = tid >> 6;
  const int wr = wave >> 1, wc = wave & 1;   // 2x2 waves, each owns 64x64 of C
  const int bm = blockIdx.x, bn = blockIdx.y;
  const int l15 = lane & 15, lg = lane >> 4;

  // staging coordinates: 4 chunks of 8 f16 elems per tile per thread
  int srow[4], skc[4], sbyte[4];
#pragma unroll
  for (int c = 0; c < 4; ++c) {
    int flat = c * 2048 + tid * 8;           // f16 element index in 128x64 tile
    srow[c]  = flat >> 6;
    skc[c]   = flat & 63;
    sbyte[c] = (flat * 2) ^ ((srow[c] & 7) << 4);
  }

  f32x4 areg[4][2], wreg[4][2];
  auto LOADG = [&](int k0) {
#pragma unroll
    for (int c = 0; c < 4; ++c) {
      const float* pa = A + (size_t)(bm*128 + srow[c]) * 1024 + k0 + skc[c];
      areg[c][0] = *reinterpret_cast<const f32x4*>(pa);
      areg[c][1] = *reinterpret_cast<const f32x4*>(pa + 4);
      const float* pw = W + (size_t)(bn*128 + srow[c]) * 1024 + k0 + skc[c];
      wreg[c][0] = *reinterpret_cast<const f32x4*>(pw);
      wreg[c][1] = *reinterpret_cast<const f32x4*>(pw + 4);
    }
  };
  auto WRITELDS = [&]() {
#pragma unroll
    for (int c = 0; c < 4; ++c) {
      f16x8 ha, hw;
#pragma unroll
      for (int i = 0; i < 4; ++i) {
        ha[i]     = (f16)areg[c][0][i];
        ha[4 + i] = (f16)areg[c][1][i];
        hw[i]     = (f16)wreg[c][0][i];
        hw[4 + i] = (f16)wreg[c][1][i];
      }
      *reinterpret_cast<f16x8*>((char*)Ash + sbyte[c]) = ha;
      *reinterpret_cast<f16x8*>((char*)Bsh + sbyte[c]) = hw;
    }
  };

  f32x4 acc[4][4] = {};

  LOADG(0);
  WRITELDS();
  __syncthreads();

  for (int k0 = 0; k0 < D_MODEL; k0 += 64) {
    if (k0 + 64 < D_MODEL) LOADG(k0 + 64);   // HBM latency hides under compute

    __builtin_amdgcn_s_setprio(1);
#pragma unroll
    for (int ks = 0; ks < 2; ++ks) {
      f16x8 af[4], bf[4];
#pragma unroll
      for (int m = 0; m < 4; ++m) {
        int r = wr*64 + m*16 + l15;
        af[m] = *reinterpret_cast<const f16x8*>(
            (const char*)Ash + r*128 + ((ks*64 + lg*16) ^ ((r & 7) << 4)));
      }
#pragma unroll
      for (int n = 0; n < 4; ++n) {
        int r = wc*64 + n*16 + l15;
        bf[n] = *reinterpret_cast<const f16x8*>(
            (const char*)Bsh + r*128 + ((ks*64 + lg*16) ^ ((r & 7) << 4)));
      }
#pragma unroll
      for (int m = 0; m < 4; ++m)
#pragma unroll
        for (int n = 0; n < 4; ++n)
          acc[m][n] = __builtin_amdgcn_mfma_f32_16x16x32_f16(af[m], bf[n], acc[m][n], 0, 0, 0);
    }
    __builtin_amdgcn_s_setprio(0);

    __syncthreads();                         // all waves done reading this tile
    if (k0 + 64 < D_MODEL) WRITELDS();       // regs(k0+64) -> LDS
    __syncthreads();                         // next tile visible
  }

  // epilogue: C/D layout col = lane&15, row = (lane>>4)*4 + j   [m89-verified]
#pragma unroll
  for (int m = 0; m < 4; ++m) {
    int rowg = bm*128 + wr*64 + m*16 + lg*4;
#pragma unroll
    for (int n = 0; n < 4; ++n) {
      int colg = bn*128 + wc*64 + n*16 + l15;
      float bvv = bias[colg];
      if (mode < 2) {
#pragma unroll
        for (int j = 0; j < 4; ++j)
          out[(size_t)(rowg + j) * D_MODEL + colg] = (f16)(acc[m][n][j] + bvv);
      } else {
        // Vt[(b*16+h)*64+dd][s], s = rowg..rowg+3 consecutive -> one 8B store
        int b = rowg >> 11, s = rowg & 2047;
        int hh = colg >> 6, dd = colg & 63;
        f16x4 pv;
#pragma unroll
        for (int j = 0; j < 4; ++j) pv[j] = (f16)(acc[m][n][j] + bvv);
        *reinterpret_cast<f16x4*>(out + (((size_t)((b*NHEAD + hh)*DH + dd)) << 11) + s) = pv;
      }
    }
  }
}

// ---------------- flash attention + residual + LayerNorm (fully fused) -------
// Swapped QK^T (S^T = mfma(K,Q)), per-lane softmax (q = lane&15), defer-max,
// reg-staged K/V, log2e folded into Q, 32 q-rows per wave (2 sub-tiles).
// Epilogue: the reference's raw-memory reshape means output row
//   sq = h*128 + qb*8 + 2*wave + qt
// is EXACTLY sub-tile qt of this wave (d = (lg*4+j)*64 + n*16 + l15), so
// residual + LN fuse here with a per-wave 64-lane butterfly — no Z buffer.
// NOTE: reference applies NO 1/sqrt(dh) scaling.
__global__ __launch_bounds__(256)
void attn_kernel(const f16* __restrict__ Q, const f16* __restrict__ K,
                 const f16* __restrict__ Vt,
                 const float* __restrict__ dec, const float* __restrict__ gamma,
                 const float* __restrict__ beta, float* __restrict__ out)
{
  __shared__ f16 Klds[64 * 64];       // [kv][d]   128B rows, XOR-swizzled
  __shared__ f16 Vlds[64 * 64];       // [dd][kv]  128B rows, XOR-swizzled
  __shared__ f16 Plds[4][2048];       // per wave: [qt][16 q][64 kk], XOR-swizzled

  const int tid = threadIdx.x, lane = tid & 63, wave = tid >> 6;
  const int l15 = lane & 15, lg = lane >> 4;
  const int qb = blockIdx.x;          // 0..15 (q block of 128)
  const int bh = blockIdx.y;          // 0..31
  const int b = bh >> 4, h = bh & 15;

  // Q fragments (B operand of swapped QK), log2e pre-folded
  f16x8 qf[2][2];
#pragma unroll
  for (int qt = 0; qt < 2; ++qt) {
    const int qrow = qb*128 + wave*32 + qt*16 + l15;
#pragma unroll
    for (int ks = 0; ks < 2; ++ks) {
      f16x8 v = *reinterpret_cast<const f16x8*>(
          Q + ((size_t)(b*SEQ + qrow)*D_MODEL + h*DH + ks*32 + lg*8));
#pragma unroll
      for (int i = 0; i < 8; ++i) v[i] = (f16)((float)v[i] * 1.44269504f);
      qf[qt][ks] = v;
    }
  }

  f32x4 oacc[2][4] = {};
  float mrun[2] = {-__builtin_inff(), -__builtin_inff()};
  float lrun[2] = {0.f, 0.f};

  const char* Kbase = (const char*)(K  + ((size_t)b*SEQ*D_MODEL + h*DH));   // + kv*2048B
  const char* Vbase = (const char*)(Vt + ((size_t)bh*DH*SEQ));              // + dd*4096B + s*2B

  uint4 kr0, kr1, vr0, vr1;
  const int off0 = tid*16,        r0 = off0 >> 7, c0 = off0 & 127;
  const int off1 = 4096 + tid*16, r1 = off1 >> 7, c1 = off1 & 127;
  const int s0 = off0 ^ ((r0 & 7) << 4);
  const int s1 = off1 ^ ((r1 & 7) << 4);

  auto LOADG = [&](int kb) {
    kr0 = *reinterpret_cast<const uint4*>(Kbase + (size_t)(kb*64 + r0)*2048 + c0);
    vr0 = *reinterpret_cast<const uint4*>(Vbase + (size_t)r0*4096 + kb*128 + c0);
    kr1 = *reinterpret_cast<const uint4*>(Kbase + (size_t)(kb*64 + r1)*2048 + c1);
    vr1 = *reinterpret_cast<const uint4*>(Vbase + (size_t)r1*4096 + kb*128 + c1);
  };
  auto WRITELDS = [&]() {
    *reinterpret_cast<uint4*>((char*)Klds + s0) = kr0;
    *reinterpret_cast<uint4*>((char*)Vlds + s0) = vr0;
    *reinterpret_cast<uint4*>((char*)Klds + s1) = kr1;
    *reinterpret_cast<uint4*>((char*)Vlds + s1) = vr1;
  };

  LOADG(0);
  WRITELDS();
  __syncthreads();

  for (int kb = 0; kb < SEQ/64; ++kb) {
    if (kb + 1 < SEQ/64) LOADG(kb + 1);   // latency hides under compute below

    // S^T = K Q^T : sacc[qt][n] tile has col=q=l15, row kk = n*16 + lg*4 + j
    f32x4 sacc[2][4] = {};
    __builtin_amdgcn_s_setprio(1);
#pragma unroll
    for (int ks = 0; ks < 2; ++ks) {
#pragma unroll
      for (int n = 0; n < 4; ++n) {
        int r = n*16 + l15;
        f16x8 kf = *reinterpret_cast<const f16x8*>(
            (const char*)Klds + r*128 + ((ks*64 + lg*16) ^ ((r & 7) << 4)));
        sacc[0][n] = __builtin_amdgcn_mfma_f32_16x16x32_f16(kf, qf[0][ks], sacc[0][n], 0, 0, 0);
        sacc[1][n] = __builtin_amdgcn_mfma_f32_16x16x32_f16(kf, qf[1][ks], sacc[1][n], 0, 0, 0);
      }
    }
    __builtin_amdgcn_s_setprio(0);

    // per-lane row max (16 kk values per qt), then 2 cross-group rounds
    float mt[2];
#pragma unroll
    for (int qt = 0; qt < 2; ++qt) {
      float m = fmaxf(fmaxf(sacc[qt][0][0], sacc[qt][0][1]),
                      fmaxf(sacc[qt][0][2], sacc[qt][0][3]));
#pragma unroll
      for (int n = 1; n < 4; ++n)
        m = fmaxf(m, fmaxf(fmaxf(sacc[qt][n][0], sacc[qt][n][1]),
                           fmaxf(sacc[qt][n][2], sacc[qt][n][3])));
      m = fmaxf(m, __shfl_xor(m, 16));
      m = fmaxf(m, __shfl_xor(m, 32));
      mt[qt] = m;
    }

    // defer-max (T13, log2 units: 8*log2e ~= 11.54)
    if (!__all(mt[0] <= mrun[0] + 11.5f && mt[1] <= mrun[1] + 11.5f)) {
#pragma unroll
      for (int qt = 0; qt < 2; ++qt) {
        float mn = fmaxf(mrun[qt], mt[qt]);
        float sc = EXP2F(mrun[qt] - mn);
        mrun[qt] = mn;
        lrun[qt] *= sc;
#pragma unroll
        for (int j = 0; j < 4; ++j) {
          float scJ = __shfl(sc, (lane & 48) | (((lane >> 4) << 2) + j), 64);
#pragma unroll
          for (int n = 0; n < 4; ++n) oacc[qt][n][j] *= scJ;
        }
      }
    }

    // P = exp2(S - mrun) (bounded by 2^11.5), packed 4-wide writes along kk
#pragma unroll
    for (int qt = 0; qt < 2; ++qt) {
      float rs = 0.f;
#pragma unroll
      for (int n = 0; n < 4; ++n) {
        f16x4 pp;
#pragma unroll
        for (int j = 0; j < 4; ++j) {
          float p = EXP2F(sacc[qt][n][j] - mrun[qt]);
          rs += p;
          pp[j] = (f16)p;
        }
        *reinterpret_cast<f16x4*>((char*)&Plds[wave][0] + qt*2048 + l15*128 +
                                  ((n*32 + lg*8) ^ ((l15 & 7) << 4))) = pp;
      }
      rs += __shfl_xor(rs, 16);
      rs += __shfl_xor(rs, 32);
      lrun[qt] += rs;
    }

    // O += P @ V  (A = P rows q=l15; B = V^T rows d)
    __builtin_amdgcn_s_setprio(1);
#pragma unroll
    for (int ks = 0; ks < 2; ++ks) {
      f16x8 pf0 = *reinterpret_cast<const f16x8*>(
          (const char*)&Plds[wave][0] + l15*128 + ((ks*64 + lg*16) ^ ((l15 & 7) << 4)));
      f16x8 pf1 = *reinterpret_cast<const f16x8*>(
          (const char*)&Plds[wave][0] + 2048 + l15*128 + ((ks*64 + lg*16) ^ ((l15 & 7) << 4)));
#pragma unroll
      for (int n = 0; n < 4; ++n) {
        int r = n*16 + l15;
        f16x8 vf = *reinterpret_cast<const f16x8*>(
            (const char*)Vlds + r*128 + ((ks*64 + lg*16) ^ ((r & 7) << 4)));
        oacc[0][n] = __builtin_amdgcn_mfma_f32_16x16x32_f16(pf0, vf, oacc[0][n], 0, 0, 0);
        oacc[1][n] = __builtin_amdgcn_mfma_f32_16x16x32_f16(pf1, vf, oacc[1][n], 0, 0, 0);
      }
    }
    __builtin_amdgcn_s_setprio(0);

    __syncthreads();                     // all waves done reading K/V tile kb
    if (kb + 1 < SEQ/64) WRITELDS();     // regs(kb+1) -> LDS (compiler waits vmcnt)
    __syncthreads();                     // tile kb+1 visible
  }

  // ---- fused epilogue: normalize + residual + LayerNorm + store -------------
  // sub-tile qt == output row sq = h*128 + qb*8 + 2*wave + qt; element
  // d = (lg*4+j)*64 + n*16 + l15. All 1024 row elements live in this wave.
#pragma unroll
  for (int qt = 0; qt < 2; ++qt) {
    float lJ[4];
#pragma unroll
    for (int j = 0; j < 4; ++j)
      lJ[j] = __shfl(lrun[qt], (lane & 48) | (((lane >> 4) << 2) + j), 64);

    const int sq = h*128 + qb*8 + 2*wave + qt;
    const float* decrow = dec + (size_t)(b*SEQ + sq) * D_MODEL;
    float x[4][4];
    float s = 0.f, ss = 0.f;
#pragma unroll
    for (int n = 0; n < 4; ++n)
#pragma unroll
      for (int j = 0; j < 4; ++j) {
        int d = (lg*4 + j)*64 + n*16 + l15;
        float v = oacc[qt][n][j] / lJ[j] + decrow[d];
        x[n][j] = v;
        s  += v;
        ss += v*v;
      }
    // 64-lane butterfly for mean/var
#pragma unroll
    for (int off = 1; off < 64; off <<= 1) {
      s  += __shfl_xor(s, off);
      ss += __shfl_xor(ss, off);
    }
    float mean = s * (1.f/1024.f);
    float var  = ss * (1.f/1024.f) - mean*mean;
    float rstd = rsqrtf(var + 1e-5f);

    float* outrow = out + (size_t)(b*SEQ + sq) * D_MODEL;
#pragma unroll
    for (int n = 0; n < 4; ++n)
#pragma unroll
      for (int j = 0; j < 4; ++j) {
        int d = (lg*4 + j)*64 + n*16 + l15;
        outrow[d] = (x[n][j] - mean)*rstd*gamma[d] + beta[d];
      }
  }
}

// ---------------- launch ----------------
extern "C" void kernel_launch(void* const* d_in, const int* in_sizes, int n_in,
                              void* d_out, int out_size, void* d_ws, size_t ws_size,
                              hipStream_t stream) {
  const float* enc   = (const float*)d_in[0];
  const float* dec   = (const float*)d_in[1];
  const float* Wq    = (const float*)d_in[2];
  const float* bq    = (const float*)d_in[3];
  const float* Wk    = (const float*)d_in[4];
  const float* bk    = (const float*)d_in[5];
  const float* Wv    = (const float*)d_in[6];
  const float* bv    = (const float*)d_in[7];
  const float* gamma = (const float*)d_in[8];
  const float* beta  = (const float*)d_in[9];
  float* out = (float*)d_out;
  uint8_t* ws = (uint8_t*)d_ws;

  // workspace layout (24 MB total)
  f16*  Qh    = (f16*)(ws);                       // 8 MB
  f16*  Kh    = (f16*)(ws + (8u  << 20));         // 8 MB
  f16*  Vth   = (f16*)(ws + (16u << 20));         // 8 MB  [B*H][64][2048]

  qkv_gemm<<<dim3(MTOT/128, D_MODEL/128, 3), 256, 0, stream>>>(
      dec, enc, Wq, Wk, Wv, bq, bk, bv, Qh, Kh, Vth);

  attn_kernel<<<dim3(SEQ/128, BATCH*NHEAD), 256, 0, stream>>>(
      Qh, Kh, Vth, dec, gamma, beta, out);
}